// Round 5
// baseline (596.807 us; speedup 1.0000x reference)
//
#include <hip/hip_runtime.h>
#include <cstdint>

typedef unsigned int u32;
typedef unsigned short u16;
typedef float fx4 __attribute__((ext_vector_type(4)));
typedef __bf16 bfx8 __attribute__((ext_vector_type(8)));

// ---------- helpers ----------
__device__ __forceinline__ u16 f2bf(float f) {
  u32 u = __builtin_bit_cast(u32, f);
  u32 r = (u + 0x7fffu + ((u >> 16) & 1u)) >> 16;  // RNE
  return (u16)r;
}
__device__ __forceinline__ float bf2f(u16 v) {
  return __builtin_bit_cast(float, (u32)v << 16);
}
// async global->LDS, 16B per lane (gfx950). LDS dest = wave-uniform base + lane*16.
__device__ __forceinline__ void async_copy16(const void* g, void* l) {
  auto gp = reinterpret_cast<__attribute__((address_space(1))) void*>((uintptr_t)g);
  auto lp = reinterpret_cast<__attribute__((address_space(3))) void*>((uintptr_t)l);
  __builtin_amdgcn_global_load_lds(gp, lp, 16, 0, 0);
}

// ---------- fp32 -> bf16 conversion of x, c, 8 weights ----------
__global__ __launch_bounds__(256) void cvt_all(
    const float* __restrict__ x, const float* __restrict__ c,
    const float* __restrict__ w0, const float* __restrict__ w1,
    const float* __restrict__ w2, const float* __restrict__ w3,
    const float* __restrict__ w4, const float* __restrict__ w5,
    const float* __restrict__ w6, const float* __restrict__ w7,
    u16* __restrict__ xb, u16* __restrict__ cb, u16* __restrict__ wb) {
  const int i = blockIdx.x * 256 + threadIdx.x;  // float4 index
  const float* src;
  u16* dst;
  size_t off;
  if (i < 4194304) {            // x: 16777216 floats
    src = x; dst = xb; off = (size_t)i;
  } else if (i < 4456448) {     // c: 1048576 floats
    src = c; dst = cb; off = (size_t)(i - 4194304);
  } else {                      // 8 weights, 1048576 floats each
    const int r = i - 4456448;
    const int wsel = r >> 18;
    off = (size_t)(r & 262143);
    switch (wsel) {
      case 0: src = w0; break; case 1: src = w1; break;
      case 2: src = w2; break; case 3: src = w3; break;
      case 4: src = w4; break; case 5: src = w5; break;
      case 6: src = w6; break; default: src = w7; break;
    }
    dst = wb + (size_t)wsel * 1048576;
  }
  const fx4 v = *(const fx4*)(src + off * 4);
  uint2 o;
  o.x = (u32)f2bf(v[0]) | ((u32)f2bf(v[1]) << 16);
  o.y = (u32)f2bf(v[2]) | ((u32)f2bf(v[3]) << 16);
  *(uint2*)(dst + off * 4) = o;
}

// ---------- 256x256 tile GEMM core, K=1024, 8-phase schedule, 8 waves, 512 thr ----------
// (verified R4: conflicts 557K, correct). Two K-tile buffers (U@0, V@32768 u16),
// each AKh0|AKh1|BKh0|BKh1 regions of 8192 u16. Packed 128B LDS rows, 8-chunk XOR
// swizzle via pre-swizzled global source. Per phase: {ds_read frag || stage 1
// half-tile -> barrier -> lgkmcnt(0) -> setprio(1) 16 MFMA setprio(0) ->
// [counted vmcnt(8) odd tails] -> barrier}. Drain 4/0 only in peeled last iter.
#define GC_DSB(BUF, KS)                                                        \
  _Pragma("unroll") for (int i_ = 0; i_ < 4; ++i_) bfr[i_] =                   \
      *(const bfx8*)(lds + (BUF) + 16384 + (KS) * 8192 + wc * 2048 + i_ * 512 + aLane);
#define GC_DSA(BUF, KS, H)                                                     \
  _Pragma("unroll") for (int i_ = 0; i_ < 4; ++i_) af[i_] =                    \
      *(const bfx8*)(lds + (BUF) + (KS) * 8192 + wr * 4096 + (H) * 2048 + i_ * 512 + aLane);
#define GC_STA(REG, KCOL)                                                      \
  async_copy16(Aop + aOff0 + (KCOL), lds + (REG) + dst0);                      \
  async_copy16(Aop + aOff1 + (KCOL), lds + (REG) + dst1);
#define GC_STB(REG, KCOL)                                                      \
  async_copy16(Bop + bOff0 + (KCOL), lds + (REG) + dst0);                      \
  async_copy16(Bop + bOff1 + (KCOL), lds + (REG) + dst1);
#define GC_MFMA(H)                                                             \
  __builtin_amdgcn_s_setprio(1);                                               \
  _Pragma("unroll") for (int mi_ = 0; mi_ < 4; ++mi_)                          \
  _Pragma("unroll") for (int ni_ = 0; ni_ < 4; ++ni_)                          \
      acc[(H) * 4 + mi_][ni_] = __builtin_amdgcn_mfma_f32_16x16x32_bf16(       \
          af[mi_], bfr[ni_], acc[(H) * 4 + mi_][ni_], 0, 0, 0);                \
  __builtin_amdgcn_s_setprio(0);
#define GC_MID()                                                               \
  __builtin_amdgcn_s_barrier();                                                \
  asm volatile("s_waitcnt lgkmcnt(0)" ::: "memory");                           \
  __builtin_amdgcn_sched_barrier(0);
#define GC_END()                                                               \
  __builtin_amdgcn_s_barrier();                                                \
  __builtin_amdgcn_sched_barrier(0);

__device__ __forceinline__ void gemm256_core(
    const u16* __restrict__ Aop, const u16* __restrict__ Bop,
    long rowBase, long colBase, u16* lds, fx4 (&acc)[8][4]) {
  const int t = threadIdx.x;           // 0..511
  const int lane = t & 63;
  const int lr = lane & 15;
  const int quad = lane >> 4;
  const int w = t >> 6;                // 0..7
  const int wr = w >> 2;               // 0..1  (M half)
  const int wc = w & 3;                // 0..3  (N quarter)
  const int phys = (((lr & 1) << 2) | quad) ^ ((lr >> 1) & 7);
  const int aLane = ((lr >> 1) << 6) + (phys << 3);

  // staging inverse-swizzle map: chunks c = t, t+512 of a 16KB half-tile
  int aOff0, aOff1, bOff0, bOff1, dst0, dst1;
  {
    const int c0 = t;
    const int R0 = c0 >> 3;
    const int lg0 = (c0 & 7) ^ (R0 & 7);
    const int m0_ = 2 * R0 + (lg0 >> 2);
    const int g0 = lg0 & 3;
    aOff0 = (int)(rowBase + m0_) * 1024 + g0 * 8;
    bOff0 = (int)(colBase + m0_) * 1024 + g0 * 8;
    dst0 = c0 * 8;
    const int c1 = t + 512;
    const int R1 = c1 >> 3;
    const int lg1 = (c1 & 7) ^ (R1 & 7);
    const int m1_ = 2 * R1 + (lg1 >> 2);
    const int g1 = lg1 & 3;
    aOff1 = (int)(rowBase + m1_) * 1024 + g1 * 8;
    bOff1 = (int)(colBase + m1_) * 1024 + g1 * 8;
    dst1 = c1 * 8;
  }

  // prologue: stage kt0 (U, both K-halves) + kt1 Kh0 (V)
  GC_STA(0, 0) GC_STB(16384, 0) GC_STA(8192, 32) GC_STB(24576, 32)
  GC_STA(32768, 64) GC_STB(49152, 64)
  asm volatile("s_waitcnt vmcnt(8)" ::: "memory");  // U.Kh0 (A+B) landed
  __builtin_amdgcn_s_barrier();
  __builtin_amdgcn_sched_barrier(0);

  bfx8 bfr[4];
  for (int it = 0; it < 8; ++it) {
    const bool lastI = (it == 7);
    const int k1 = (2 * it + 1) * 64 + 32;  // V.Kh1 of kt 2it+1 (always real)
    const int k2 = (2 * it + 2) * 64;       // U' Kh0
    const int k3 = k2 + 32;                 // U' Kh1
    const int k4 = (2 * it + 3) * 64;       // V' Kh0
    // p0: U h0 ks0 | stage V.AKh1
    { bfx8 af[4];
      GC_DSB(0, 0) GC_DSA(0, 0, 0)
      GC_STA(40960, k1)
      GC_MID() GC_MFMA(0) GC_END() }
    // p1: U h1 ks0 | stage V.BKh1 | vmcnt(8)
    { bfx8 af[4];
      GC_DSA(0, 0, 1)
      GC_STB(57344, k1)
      GC_MID() GC_MFMA(1)
      asm volatile("s_waitcnt vmcnt(8)" ::: "memory");
      GC_END() }
    // p2: U h0 ks1 | stage U'.AKh0
    { bfx8 af[4];
      GC_DSB(0, 1) GC_DSA(0, 1, 0)
      if (!lastI) { GC_STA(0, k2) }
      GC_MID() GC_MFMA(0) GC_END() }
    // p3: U h1 ks1 | stage U'.BKh0 | vmcnt(8) (last iter: 4)
    { bfx8 af[4];
      GC_DSA(0, 1, 1)
      if (!lastI) { GC_STB(16384, k2) }
      GC_MID() GC_MFMA(1)
      if (lastI) { asm volatile("s_waitcnt vmcnt(4)" ::: "memory"); }
      else       { asm volatile("s_waitcnt vmcnt(8)" ::: "memory"); }
      GC_END() }
    // p4: V h0 ks0 | stage U'.AKh1
    { bfx8 af[4];
      GC_DSB(32768, 0) GC_DSA(32768, 0, 0)
      if (!lastI) { GC_STA(8192, k3) }
      GC_MID() GC_MFMA(0) GC_END() }
    // p5: V h1 ks0 | stage U'.BKh1 | vmcnt(8) (last iter: 0)
    { bfx8 af[4];
      GC_DSA(32768, 0, 1)
      if (!lastI) { GC_STB(24576, k3) }
      GC_MID() GC_MFMA(1)
      if (lastI) { asm volatile("s_waitcnt vmcnt(0)" ::: "memory"); }
      else       { asm volatile("s_waitcnt vmcnt(8)" ::: "memory"); }
      GC_END() }
    // p6: V h0 ks1 | stage V'.AKh0
    { bfx8 af[4];
      GC_DSB(32768, 1) GC_DSA(32768, 1, 0)
      if (!lastI) { GC_STA(32768, k4) }
      GC_MID() GC_MFMA(0) GC_END() }
    // p7: V h1 ks1 | stage V'.BKh0 | vmcnt(8)
    { bfx8 af[4];
      GC_DSA(32768, 1, 1)
      if (!lastI) { GC_STB(49152, k4) }
      GC_MID() GC_MFMA(1)
      if (!lastI) { asm volatile("s_waitcnt vmcnt(8)" ::: "memory"); }
      GC_END() }
  }
}

// ---------- fused projections: all 6 QKV GEMMs in one dispatch ----------
// XCD chunked swizzle: work u = yy*12 + xx (A-panel-major); u = (bid%8)*102 +
// bid/8 gives each XCD a contiguous ~8.5-panel row range -> A fetched into ONE
// L2, not replicated 8x. 816 % 8 == 0 -> bijective.
__global__ __launch_bounds__(512, 2) void proj_fused(
    const u16* __restrict__ Xb, const u16* __restrict__ Cb, const u16* __restrict__ Wb,
    u16* __restrict__ Qx, u16* __restrict__ Qc,
    u16* __restrict__ Kt, u16* __restrict__ Vt,
    const float* __restrict__ nc) {
  extern __shared__ __align__(16) u16 lds[];
  const int bid = (int)(blockIdx.y * 12 + blockIdx.x);
  const int u = (bid & 7) * 102 + (bid >> 3);
  const int yy = u / 12;
  const int xx = u - yy * 12;
  const bool isC = yy >= 64;
  const u16* A = isC ? Cb : Xb;
  const u16* Bw = Wb + (isC ? 3145728 : 0);  // c-stream weights at +3*1024*1024
  const long rowBase = (long)(isC ? yy - 64 : yy) * 256;
  const long colBase = (long)xx * 256;

  fx4 acc[8][4] = {};
  gemm256_core(A, Bw, rowBase, colBase, lds, acc);

  const int t = threadIdx.x;
  const int lane = t & 63;
  const int lr = lane & 15;
  const int quad = lane >> 4;
  const int w = t >> 6;
  const int wr = w >> 2;
  const int wc = w & 3;
  const long wRowBase = rowBase + wr * 128;

  const long col0 = colBase + wc * 64;   // 64-aligned: wave covers one head segment
  const int col64 = (int)(col0 >> 6);    // 0..47
  const int sel = col64 >> 4;            // 0=q, 1=k, 2=v  (uniform per block)
  const int h = col64 & 15;
  const int lcolBase = (int)(col0 & 1023);

  if (sel == 0) {
    // Q: per-row l2norm, row-major store (feeds out_fused A-operand)
    u16* dst = isC ? Qc : Qx;
#pragma unroll
    for (int mi = 0; mi < 8; ++mi) {
      float ss[4] = {0.f, 0.f, 0.f, 0.f};
#pragma unroll
      for (int ni = 0; ni < 4; ++ni)
#pragma unroll
        for (int r = 0; r < 4; ++r) ss[r] += acc[mi][ni][r] * acc[mi][ni][r];
#pragma unroll
      for (int off = 1; off < 16; off <<= 1)
#pragma unroll
        for (int r = 0; r < 4; ++r) ss[r] += __shfl_xor(ss[r], off, 64);
      float sc[4];
#pragma unroll
      for (int r = 0; r < 4; ++r) sc[r] = 1.f / fmaxf(sqrtf(ss[r]), 1e-12f);
#pragma unroll
      for (int ni = 0; ni < 4; ++ni) {
        const long col = lcolBase + ni * 16 + lr;
#pragma unroll
        for (int r = 0; r < 4; ++r) {
          const long row = wRowBase + mi * 16 + quad * 4 + r;
          dst[row * 1024 + col] = f2bf(acc[mi][ni][r] * sc[r]);
        }
      }
    }
  } else {
    // K (l2norm) / V (scale): per-wave LDS transpose -> Kt/Vt[b,h][d][0..4352)
    __syncthreads();  // full drain: seal gemm LDS reads before reuse
    u16* LT = lds + w * 8192;  // 16KB per wave: [d=64][128 n], n-group ^ (d&15)
    u16* T = (sel == 1) ? Kt : Vt;
    int b, nglob0;
    if (!isC) { b = (int)(wRowBase >> 12); nglob0 = (int)(wRowBase & 4095); }
    else      { b = (int)(wRowBase >> 8);  nglob0 = 4096 + (int)(wRowBase & 255); }
    u16* Tw = T + (size_t)(b * 16 + h) * 64 * 4352;
    const float vs = __expf(-8.3783908f / (1.f + __expf(-nc[h])));  // 4352^-sigmoid

#pragma unroll
    for (int mi = 0; mi < 8; ++mi) {
      float sc[4];
      if (sel == 1) {
        float ss[4] = {0.f, 0.f, 0.f, 0.f};
#pragma unroll
        for (int ni = 0; ni < 4; ++ni)
#pragma unroll
          for (int r = 0; r < 4; ++r) ss[r] += acc[mi][ni][r] * acc[mi][ni][r];
#pragma unroll
      for (int off = 1; off < 16; off <<= 1)
#pragma unroll
          for (int r = 0; r < 4; ++r) ss[r] += __shfl_xor(ss[r], off, 64);
#pragma unroll
        for (int r = 0; r < 4; ++r) sc[r] = 1.f / fmaxf(sqrtf(ss[r]), 1e-12f);
      } else {
#pragma unroll
        for (int r = 0; r < 4; ++r) sc[r] = vs;
      }
      const int g = mi * 2 + (quad >> 1);   // n-group (n_local = mi*16+quad*4+r)
      const int sub = (quad & 1) * 4;
#pragma unroll
      for (int ni = 0; ni < 4; ++ni) {
        const int d = ni * 16 + lr;
        uint2 o;
        o.x = (u32)f2bf(acc[mi][ni][0] * sc[0]) | ((u32)f2bf(acc[mi][ni][1] * sc[1]) << 16);
        o.y = (u32)f2bf(acc[mi][ni][2] * sc[2]) | ((u32)f2bf(acc[mi][ni][3] * sc[3]) << 16);
        *(uint2*)&LT[d * 128 + ((g ^ (d & 15)) << 3) + sub] = o;
      }
    }
    __syncthreads();  // uniform (sel uniform per block); orders LDS writes
    const int d = lane;
    u16* drow = Tw + (size_t)d * 4352 + nglob0;
#pragma unroll
    for (int j = 0; j < 16; ++j) {
      const uint4 qv = *(const uint4*)&LT[d * 128 + ((j ^ (d & 15)) << 3)];
      *(uint4*)&drow[j * 8] = qv;
    }
  }
}

// ---------- kv via MFMA: kv[bh][e][d] = sum_n K[n,d] V[n,e]  (stored transposed) ----------
// R5: grid (64, 17) -> 1088 blocks (was 64: only 25% of CUs). Each wave owns ONE
// 64-wide K-step (17 y-blocks x 4 waves = 68 steps exactly); per-block 4-way LDS
// reduce kept; final store -> atomicAdd into zeroed kvb.
__global__ __launch_bounds__(256) void kv_mfma(
    const u16* __restrict__ Kt, const u16* __restrict__ Vt, float* __restrict__ kvb) {
  __shared__ __align__(16) u16 TT[4][2][4096];  // per wave: K tile, V tile (64x64 u16)
  const int bh = blockIdx.x;
  const int t = threadIdx.x;
  const int w = t >> 6;
  const int lane = t & 63;
  const int lr = lane & 15;
  const int quad = lane >> 4;
  const u16* Ksrc = Kt + (size_t)bh * 64 * 4352;
  const u16* Vsrc = Vt + (size_t)bh * 64 * 4352;
  const int row8 = lane >> 3;
  const int gst = lane & 7;
  fx4 acc[4][4] = {};

  const int kbase = (blockIdx.y * 4 + w) * 64;  // this wave's K-step
#pragma unroll
  for (int i = 0; i < 8; ++i) {
    const int row = i * 8 + row8;
    const int col = ((gst ^ (row & 7)) << 3);
    const size_t go = (size_t)row * 4352 + kbase + col;
    async_copy16(Ksrc + go, &TT[w][0][i * 512 + lane * 8]);
    async_copy16(Vsrc + go, &TT[w][1][i * 512 + lane * 8]);
  }
  __syncthreads();
#pragma unroll
  for (int ks = 0; ks < 2; ++ks) {
    bfx8 af[4], bfr[4];
    const int g = ((ks * 4 + quad) ^ (lr & 7)) << 3;
#pragma unroll
    for (int i = 0; i < 4; ++i) af[i] = *(const bfx8*)&TT[w][0][(i * 16 + lr) * 64 + g];
#pragma unroll
    for (int i = 0; i < 4; ++i) bfr[i] = *(const bfx8*)&TT[w][1][(i * 16 + lr) * 64 + g];
#pragma unroll
    for (int mi = 0; mi < 4; ++mi)
#pragma unroll
      for (int ni = 0; ni < 4; ++ni)
        acc[mi][ni] =
            __builtin_amdgcn_mfma_f32_16x16x32_bf16(af[mi], bfr[ni], acc[mi][ni], 0, 0, 0);
  }
  __syncthreads();
  // per-wave partial C^T [e][d] f32, d-group swizzled; then 4-way reduce
  float* red = (float*)&TT[0][0][0];  // 16384 f32
  float* my = red + w * 4096;
#pragma unroll
  for (int mi = 0; mi < 4; ++mi)
#pragma unroll
    for (int ni = 0; ni < 4; ++ni) {
      const int e = ni * 16 + lr;
      const int dg = mi * 4 + quad;      // d = dg*4 + r, r consecutive in acc
      *(fx4*)&my[e * 64 + ((dg ^ (e & 15)) << 2)] = acc[mi][ni];
    }
  __syncthreads();
  float* outp = kvb + (size_t)bh * 4096;
#pragma unroll
  for (int j = 0; j < 4; ++j) {
    const int L = t * 16 + j * 4;        // flat [e][d] index
    const int e = L >> 6;
    const int dg = (L >> 2) & 15;
    const int addr = e * 64 + ((dg ^ (e & 15)) << 2);
    fx4 sv = *(const fx4*)&red[addr];
    sv += *(const fx4*)&red[4096 + addr];
    sv += *(const fx4*)&red[8192 + addr];
    sv += *(const fx4*)&red[12288 + addr];
    atomicAdd(&outp[L + 0], sv[0]);
    atomicAdd(&outp[L + 1], sv[1]);
    atomicAdd(&outp[L + 2], sv[2]);
    atomicAdd(&outp[L + 3], sv[3]);
  }
}

// ---------- Weff[b][o, h*64+d] = sum_e Wo[o, h*64+e] * kv[b,h][d,e]  (bf16 out) ----------
// kvb holds kv transposed: kvb[bh][e*64+d].
__global__ __launch_bounds__(256) void weff_build(
    const u16* __restrict__ WoX, const u16* __restrict__ WoC,
    const float* __restrict__ kvb, u16* __restrict__ WeffX, u16* __restrict__ WeffC) {
  const int ot = blockIdx.x;
  const int bh = blockIdx.y;
  const int b = bh >> 4, h = bh & 15;
  const u16* Wo = blockIdx.z ? WoC : WoX;
  u16* outp = (blockIdx.z ? WeffC : WeffX) + (size_t)b * 1048576;

  __shared__ __align__(16) float kvT[64 * 64];  // [e][d] = kvb layout, direct copy
  __shared__ __align__(16) float WoT[64 * 64];  // [e][o_local]
  const int t = threadIdx.x;
#pragma unroll
  for (int j = 0; j < 4; ++j) {
    const int idx = (t + 256 * j) * 4;
    *(fx4*)&kvT[idx] = *(const fx4*)&kvb[(size_t)bh * 4096 + idx];
  }
#pragma unroll
  for (int j = 0; j < 2; ++j) {
    const int u = t + 256 * j;  // 512 groups of 8 bf16
    const int row = u >> 3;     // o_local
    const int e0 = (u & 7) * 8;
    const uint4 q = *(const uint4*)&Wo[(size_t)(ot * 64 + row) * 1024 + h * 64 + e0];
    WoT[(e0 + 0) * 64 + row] = bf2f((u16)(q.x & 0xffff));
    WoT[(e0 + 1) * 64 + row] = bf2f((u16)(q.x >> 16));
    WoT[(e0 + 2) * 64 + row] = bf2f((u16)(q.y & 0xffff));
    WoT[(e0 + 3) * 64 + row] = bf2f((u16)(q.y >> 16));
    WoT[(e0 + 4) * 64 + row] = bf2f((u16)(q.z & 0xffff));
    WoT[(e0 + 5) * 64 + row] = bf2f((u16)(q.z >> 16));
    WoT[(e0 + 6) * 64 + row] = bf2f((u16)(q.w & 0xffff));
    WoT[(e0 + 7) * 64 + row] = bf2f((u16)(q.w >> 16));
  }
  __syncthreads();
  const int ob = (t >> 4) * 4;  // o_local base
  const int db = (t & 15) * 4;  // d base
  float acc[4][4] = {};
#pragma unroll 4
  for (int e = 0; e < 64; ++e) {
    const fx4 wv = *(const fx4*)&WoT[e * 64 + ob];
    const fx4 kvv = *(const fx4*)&kvT[e * 64 + db];
#pragma unroll
    for (int i = 0; i < 4; ++i)
#pragma unroll
      for (int j = 0; j < 4; ++j)
        acc[i][j] += wv[i] * kvv[j];
  }
#pragma unroll
  for (int i = 0; i < 4; ++i)
#pragma unroll
    for (int j = 0; j < 4; ++j)
      outp[(size_t)(ot * 64 + ob + i) * 1024 + h * 64 + db + j] = f2bf(acc[i][j]);
}

// ---------- fused output GEMMs: out = q @ Weff[b]^T for x and c streams ----------
// XCD chunked swizzle: u = yt*4 + xx; u = (bid%8)*34 + bid/8 (272 % 8 == 0).
__global__ __launch_bounds__(512, 2) void out_fused(
    const u16* __restrict__ Qx, const u16* __restrict__ Qc,
    const u16* __restrict__ Wex, const u16* __restrict__ Wec,
    float* __restrict__ out) {
  extern __shared__ __align__(16) u16 lds[];
  const int bid = (int)(blockIdx.y * 4 + blockIdx.x);
  const int u = (bid & 7) * 34 + (bid >> 3);
  const int yt = u >> 2;
  const int xx = u & 3;
  const int b = yt / 17;
  const int l = yt - b * 17;
  const bool isC = (l == 16);
  const u16* A;
  const u16* Bw;
  float* C;
  long rowBase;
  if (!isC) {
    A = Qx + (size_t)b * 4194304;
    Bw = Wex + (size_t)b * 1048576;
    C = out + (size_t)b * 4194304;
    rowBase = (long)l * 256;
  } else {
    A = Qc + (size_t)b * 262144;
    Bw = Wec + (size_t)b * 1048576;
    C = out + 16777216 + (size_t)b * 262144;
    rowBase = 0;
  }
  const long colBase = (long)xx * 256;

  fx4 acc[8][4] = {};
  gemm256_core(A, Bw, rowBase, colBase, lds, acc);

  const int t = threadIdx.x;
  const int lane = t & 63;
  const int lr = lane & 15;
  const int quad = lane >> 4;
  const int w = t >> 6;
  const int wr = w >> 2;
  const int wc = w & 3;
#pragma unroll
  for (int mi = 0; mi < 8; ++mi)
#pragma unroll
    for (int ni = 0; ni < 4; ++ni) {
      const long col = colBase + wc * 64 + ni * 16 + lr;
#pragma unroll
      for (int r = 0; r < 4; ++r) {
        const long row = rowBase + wr * 128 + mi * 16 + quad * 4 + r;
        C[row * 1024 + col] = acc[mi][ni][r];
      }
    }
}

// ---------- launch ----------
extern "C" void kernel_launch(void* const* d_in, const int* in_sizes, int n_in,
                              void* d_out, int out_size, void* d_ws, size_t ws_size,
                              hipStream_t stream) {
  (void)in_sizes; (void)n_in; (void)out_size; (void)ws_size;
  const float* x = (const float*)d_in[0];
  const float* c = (const float*)d_in[1];
  const float* nc = (const float*)d_in[10];
  float* out = (float*)d_out;
  char* ws = (char*)d_ws;

  static bool attr_done = false;
  if (!attr_done) {
    hipFuncSetAttribute((const void*)proj_fused,
                        hipFuncAttributeMaxDynamicSharedMemorySize, 131072);
    hipFuncSetAttribute((const void*)out_fused,
                        hipFuncAttributeMaxDynamicSharedMemorySize, 131072);
    attr_done = true;
  }

  // workspace layout (bytes). total = 177,209,344
  u16* Xb = (u16*)(ws + 0);                 // 33,554,432
  u16* Cb = (u16*)(ws + 33554432);          //  2,097,152
  u16* Wb = (u16*)(ws + 35651584);          // 16,777,216 (8 weights bf16)
  u16* Qx = (u16*)(ws + 52428800);          // 33,554,432
  u16* Qc = (u16*)(ws + 85983232);          //  2,097,152
  u16* Kt = (u16*)(ws + 88080384);          // 35,651,584  [b,h][64 d][4352 n]
  u16* Vt = (u16*)(ws + 123731968);         // 35,651,584
  float* kvb = (float*)(ws + 159383552);    //  1,048,576  kv^T: [bh][e*64+d]
  u16* Weffx = (u16*)(ws + 160432128);      //  8,388,608
  u16* Weffc = (u16*)(ws + 168820736);      //  8,388,608

  // zero kv accumulator (kv_mfma now atomically accumulates across 17 y-blocks)
  hipMemsetAsync(kvb, 0, 1048576, stream);

  cvt_all<<<25600, 256, 0, stream>>>(
      x, c, (const float*)d_in[2], (const float*)d_in[3], (const float*)d_in[4],
      (const float*)d_in[5], (const float*)d_in[6], (const float*)d_in[7],
      (const float*)d_in[8], (const float*)d_in[9], Xb, Cb, Wb);

  // all 6 QKV projections in one dispatch (Q row-major; K,V transposed)
  proj_fused<<<dim3(12, 68), 512, 131072, stream>>>(Xb, Cb, Wb, Qx, Qc, Kt, Vt, nc);
  // kv = K^T V per (b,h), MFMA, 1088 blocks, atomic accumulate
  kv_mfma<<<dim3(64, 17), 256, 0, stream>>>(Kt, Vt, kvb);
  // fold kv into output projections: Weff[b] = blockdiag(kv) applied to Wo
  weff_build<<<dim3(16, 64, 2), 256, 0, stream>>>(Wb + 6 * 1048576, Wb + 7 * 1048576,
                                                  kvb, Weffx, Weffc);
  // both output GEMMs in one dispatch, straight into d_out (fp32)
  out_fused<<<dim3(4, 68), 512, 131072, stream>>>(Qx, Qc, Weffx, Weffc, out);
}

// Round 6
// 399.587 us; speedup vs baseline: 1.4936x; 1.4936x over previous
//
#include <hip/hip_runtime.h>
#include <cstdint>

typedef unsigned int u32;
typedef unsigned short u16;
typedef float fx4 __attribute__((ext_vector_type(4)));
typedef __bf16 bfx8 __attribute__((ext_vector_type(8)));

// ---------- helpers ----------
__device__ __forceinline__ u16 f2bf(float f) {
  u32 u = __builtin_bit_cast(u32, f);
  u32 r = (u + 0x7fffu + ((u >> 16) & 1u)) >> 16;  // RNE
  return (u16)r;
}
__device__ __forceinline__ float bf2f(u16 v) {
  return __builtin_bit_cast(float, (u32)v << 16);
}
// async global->LDS, 16B per lane (gfx950). LDS dest = wave-uniform base + lane*16.
__device__ __forceinline__ void async_copy16(const void* g, void* l) {
  auto gp = reinterpret_cast<__attribute__((address_space(1))) void*>((uintptr_t)g);
  auto lp = reinterpret_cast<__attribute__((address_space(3))) void*>((uintptr_t)l);
  __builtin_amdgcn_global_load_lds(gp, lp, 16, 0, 0);
}

// ---------- fp32 -> bf16 conversion of x, c, 8 weights ----------
__global__ __launch_bounds__(256) void cvt_all(
    const float* __restrict__ x, const float* __restrict__ c,
    const float* __restrict__ w0, const float* __restrict__ w1,
    const float* __restrict__ w2, const float* __restrict__ w3,
    const float* __restrict__ w4, const float* __restrict__ w5,
    const float* __restrict__ w6, const float* __restrict__ w7,
    u16* __restrict__ xb, u16* __restrict__ cb, u16* __restrict__ wb) {
  const int i = blockIdx.x * 256 + threadIdx.x;  // float4 index
  const float* src;
  u16* dst;
  size_t off;
  if (i < 4194304) {            // x: 16777216 floats
    src = x; dst = xb; off = (size_t)i;
  } else if (i < 4456448) {     // c: 1048576 floats
    src = c; dst = cb; off = (size_t)(i - 4194304);
  } else {                      // 8 weights, 1048576 floats each
    const int r = i - 4456448;
    const int wsel = r >> 18;
    off = (size_t)(r & 262143);
    switch (wsel) {
      case 0: src = w0; break; case 1: src = w1; break;
      case 2: src = w2; break; case 3: src = w3; break;
      case 4: src = w4; break; case 5: src = w5; break;
      case 6: src = w6; break; default: src = w7; break;
    }
    dst = wb + (size_t)wsel * 1048576;
  }
  const fx4 v = *(const fx4*)(src + off * 4);
  uint2 o;
  o.x = (u32)f2bf(v[0]) | ((u32)f2bf(v[1]) << 16);
  o.y = (u32)f2bf(v[2]) | ((u32)f2bf(v[3]) << 16);
  *(uint2*)(dst + off * 4) = o;
}

// ---------- 256x256 tile GEMM core, K=1024, 8-phase schedule, 8 waves, 512 thr ----------
// (verified R4: conflicts 557K, correct). Two K-tile buffers (U@0, V@32768 u16),
// each AKh0|AKh1|BKh0|BKh1 regions of 8192 u16. Packed 128B LDS rows, 8-chunk XOR
// swizzle via pre-swizzled global source. Per phase: {ds_read frag || stage 1
// half-tile -> barrier -> lgkmcnt(0) -> setprio(1) 16 MFMA setprio(0) ->
// [counted vmcnt(8) odd tails] -> barrier}. Drain 4/0 only in peeled last iter.
#define GC_DSB(BUF, KS)                                                        \
  _Pragma("unroll") for (int i_ = 0; i_ < 4; ++i_) bfr[i_] =                   \
      *(const bfx8*)(lds + (BUF) + 16384 + (KS) * 8192 + wc * 2048 + i_ * 512 + aLane);
#define GC_DSA(BUF, KS, H)                                                     \
  _Pragma("unroll") for (int i_ = 0; i_ < 4; ++i_) af[i_] =                    \
      *(const bfx8*)(lds + (BUF) + (KS) * 8192 + wr * 4096 + (H) * 2048 + i_ * 512 + aLane);
#define GC_STA(REG, KCOL)                                                      \
  async_copy16(Aop + aOff0 + (KCOL), lds + (REG) + dst0);                      \
  async_copy16(Aop + aOff1 + (KCOL), lds + (REG) + dst1);
#define GC_STB(REG, KCOL)                                                      \
  async_copy16(Bop + bOff0 + (KCOL), lds + (REG) + dst0);                      \
  async_copy16(Bop + bOff1 + (KCOL), lds + (REG) + dst1);
#define GC_MFMA(H)                                                             \
  __builtin_amdgcn_s_setprio(1);                                               \
  _Pragma("unroll") for (int mi_ = 0; mi_ < 4; ++mi_)                          \
  _Pragma("unroll") for (int ni_ = 0; ni_ < 4; ++ni_)                          \
      acc[(H) * 4 + mi_][ni_] = __builtin_amdgcn_mfma_f32_16x16x32_bf16(       \
          af[mi_], bfr[ni_], acc[(H) * 4 + mi_][ni_], 0, 0, 0);                \
  __builtin_amdgcn_s_setprio(0);
#define GC_MID()                                                               \
  __builtin_amdgcn_s_barrier();                                                \
  asm volatile("s_waitcnt lgkmcnt(0)" ::: "memory");                           \
  __builtin_amdgcn_sched_barrier(0);
#define GC_END()                                                               \
  __builtin_amdgcn_s_barrier();                                                \
  __builtin_amdgcn_sched_barrier(0);

__device__ __forceinline__ void gemm256_core(
    const u16* __restrict__ Aop, const u16* __restrict__ Bop,
    long rowBase, long colBase, u16* lds, fx4 (&acc)[8][4]) {
  const int t = threadIdx.x;           // 0..511
  const int lane = t & 63;
  const int lr = lane & 15;
  const int quad = lane >> 4;
  const int w = t >> 6;                // 0..7
  const int wr = w >> 2;               // 0..1  (M half)
  const int wc = w & 3;                // 0..3  (N quarter)
  const int phys = (((lr & 1) << 2) | quad) ^ ((lr >> 1) & 7);
  const int aLane = ((lr >> 1) << 6) + (phys << 3);

  // staging inverse-swizzle map: chunks c = t, t+512 of a 16KB half-tile
  int aOff0, aOff1, bOff0, bOff1, dst0, dst1;
  {
    const int c0 = t;
    const int R0 = c0 >> 3;
    const int lg0 = (c0 & 7) ^ (R0 & 7);
    const int m0_ = 2 * R0 + (lg0 >> 2);
    const int g0 = lg0 & 3;
    aOff0 = (int)(rowBase + m0_) * 1024 + g0 * 8;
    bOff0 = (int)(colBase + m0_) * 1024 + g0 * 8;
    dst0 = c0 * 8;
    const int c1 = t + 512;
    const int R1 = c1 >> 3;
    const int lg1 = (c1 & 7) ^ (R1 & 7);
    const int m1_ = 2 * R1 + (lg1 >> 2);
    const int g1 = lg1 & 3;
    aOff1 = (int)(rowBase + m1_) * 1024 + g1 * 8;
    bOff1 = (int)(colBase + m1_) * 1024 + g1 * 8;
    dst1 = c1 * 8;
  }

  // prologue: stage kt0 (U, both K-halves) + kt1 Kh0 (V)
  GC_STA(0, 0) GC_STB(16384, 0) GC_STA(8192, 32) GC_STB(24576, 32)
  GC_STA(32768, 64) GC_STB(49152, 64)
  asm volatile("s_waitcnt vmcnt(8)" ::: "memory");  // U.Kh0 (A+B) landed
  __builtin_amdgcn_s_barrier();
  __builtin_amdgcn_sched_barrier(0);

  bfx8 bfr[4];
  for (int it = 0; it < 8; ++it) {
    const bool lastI = (it == 7);
    const int k1 = (2 * it + 1) * 64 + 32;  // V.Kh1 of kt 2it+1 (always real)
    const int k2 = (2 * it + 2) * 64;       // U' Kh0
    const int k3 = k2 + 32;                 // U' Kh1
    const int k4 = (2 * it + 3) * 64;       // V' Kh0
    // p0: U h0 ks0 | stage V.AKh1
    { bfx8 af[4];
      GC_DSB(0, 0) GC_DSA(0, 0, 0)
      GC_STA(40960, k1)
      GC_MID() GC_MFMA(0) GC_END() }
    // p1: U h1 ks0 | stage V.BKh1 | vmcnt(8)
    { bfx8 af[4];
      GC_DSA(0, 0, 1)
      GC_STB(57344, k1)
      GC_MID() GC_MFMA(1)
      asm volatile("s_waitcnt vmcnt(8)" ::: "memory");
      GC_END() }
    // p2: U h0 ks1 | stage U'.AKh0
    { bfx8 af[4];
      GC_DSB(0, 1) GC_DSA(0, 1, 0)
      if (!lastI) { GC_STA(0, k2) }
      GC_MID() GC_MFMA(0) GC_END() }
    // p3: U h1 ks1 | stage U'.BKh0 | vmcnt(8) (last iter: 4)
    { bfx8 af[4];
      GC_DSA(0, 1, 1)
      if (!lastI) { GC_STB(16384, k2) }
      GC_MID() GC_MFMA(1)
      if (lastI) { asm volatile("s_waitcnt vmcnt(4)" ::: "memory"); }
      else       { asm volatile("s_waitcnt vmcnt(8)" ::: "memory"); }
      GC_END() }
    // p4: V h0 ks0 | stage U'.AKh1
    { bfx8 af[4];
      GC_DSB(32768, 0) GC_DSA(32768, 0, 0)
      if (!lastI) { GC_STA(8192, k3) }
      GC_MID() GC_MFMA(0) GC_END() }
    // p5: V h1 ks0 | stage U'.BKh1 | vmcnt(8) (last iter: 0)
    { bfx8 af[4];
      GC_DSA(32768, 0, 1)
      if (!lastI) { GC_STB(24576, k3) }
      GC_MID() GC_MFMA(1)
      if (lastI) { asm volatile("s_waitcnt vmcnt(0)" ::: "memory"); }
      else       { asm volatile("s_waitcnt vmcnt(8)" ::: "memory"); }
      GC_END() }
    // p6: V h0 ks1 | stage V'.AKh0
    { bfx8 af[4];
      GC_DSB(32768, 1) GC_DSA(32768, 1, 0)
      if (!lastI) { GC_STA(32768, k4) }
      GC_MID() GC_MFMA(0) GC_END() }
    // p7: V h1 ks1 | stage V'.BKh0 | vmcnt(8)
    { bfx8 af[4];
      GC_DSA(32768, 1, 1)
      if (!lastI) { GC_STB(49152, k4) }
      GC_MID() GC_MFMA(1)
      if (!lastI) { asm volatile("s_waitcnt vmcnt(8)" ::: "memory"); }
      GC_END() }
  }
}

// ---------- fused projections: all 6 QKV GEMMs in one dispatch ----------
// XCD chunked swizzle: work u = yy*12 + xx (A-panel-major); u = (bid%8)*102 +
// bid/8 gives each XCD a contiguous ~8.5-panel row range -> A fetched into ONE
// L2, not replicated 8x. 816 % 8 == 0 -> bijective.
__global__ __launch_bounds__(512, 2) void proj_fused(
    const u16* __restrict__ Xb, const u16* __restrict__ Cb, const u16* __restrict__ Wb,
    u16* __restrict__ Qx, u16* __restrict__ Qc,
    u16* __restrict__ Kt, u16* __restrict__ Vt,
    const float* __restrict__ nc) {
  extern __shared__ __align__(16) u16 lds[];
  const int bid = (int)(blockIdx.y * 12 + blockIdx.x);
  const int u = (bid & 7) * 102 + (bid >> 3);
  const int yy = u / 12;
  const int xx = u - yy * 12;
  const bool isC = yy >= 64;
  const u16* A = isC ? Cb : Xb;
  const u16* Bw = Wb + (isC ? 3145728 : 0);  // c-stream weights at +3*1024*1024
  const long rowBase = (long)(isC ? yy - 64 : yy) * 256;
  const long colBase = (long)xx * 256;

  fx4 acc[8][4] = {};
  gemm256_core(A, Bw, rowBase, colBase, lds, acc);

  const int t = threadIdx.x;
  const int lane = t & 63;
  const int lr = lane & 15;
  const int quad = lane >> 4;
  const int w = t >> 6;
  const int wr = w >> 2;
  const int wc = w & 3;
  const long wRowBase = rowBase + wr * 128;

  const long col0 = colBase + wc * 64;   // 64-aligned: wave covers one head segment
  const int col64 = (int)(col0 >> 6);    // 0..47
  const int sel = col64 >> 4;            // 0=q, 1=k, 2=v  (uniform per block)
  const int h = col64 & 15;
  const int lcolBase = (int)(col0 & 1023);

  if (sel == 0) {
    // Q: per-row l2norm, row-major store (feeds out_fused A-operand)
    u16* dst = isC ? Qc : Qx;
#pragma unroll
    for (int mi = 0; mi < 8; ++mi) {
      float ss[4] = {0.f, 0.f, 0.f, 0.f};
#pragma unroll
      for (int ni = 0; ni < 4; ++ni)
#pragma unroll
        for (int r = 0; r < 4; ++r) ss[r] += acc[mi][ni][r] * acc[mi][ni][r];
#pragma unroll
      for (int off = 1; off < 16; off <<= 1)
#pragma unroll
        for (int r = 0; r < 4; ++r) ss[r] += __shfl_xor(ss[r], off, 64);
      float sc[4];
#pragma unroll
      for (int r = 0; r < 4; ++r) sc[r] = 1.f / fmaxf(sqrtf(ss[r]), 1e-12f);
#pragma unroll
      for (int ni = 0; ni < 4; ++ni) {
        const long col = lcolBase + ni * 16 + lr;
#pragma unroll
        for (int r = 0; r < 4; ++r) {
          const long row = wRowBase + mi * 16 + quad * 4 + r;
          dst[row * 1024 + col] = f2bf(acc[mi][ni][r] * sc[r]);
        }
      }
    }
  } else {
    // K (l2norm) / V (scale): per-wave LDS transpose -> Kt/Vt[b,h][d][0..4352)
    __syncthreads();  // full drain: seal gemm LDS reads before reuse
    u16* LT = lds + w * 8192;  // 16KB per wave: [d=64][128 n], n-group ^ (d&15)
    u16* T = (sel == 1) ? Kt : Vt;
    int b, nglob0;
    if (!isC) { b = (int)(wRowBase >> 12); nglob0 = (int)(wRowBase & 4095); }
    else      { b = (int)(wRowBase >> 8);  nglob0 = 4096 + (int)(wRowBase & 255); }
    u16* Tw = T + (size_t)(b * 16 + h) * 64 * 4352;
    const float vs = __expf(-8.3783908f / (1.f + __expf(-nc[h])));  // 4352^-sigmoid

#pragma unroll
    for (int mi = 0; mi < 8; ++mi) {
      float sc[4];
      if (sel == 1) {
        float ss[4] = {0.f, 0.f, 0.f, 0.f};
#pragma unroll
        for (int ni = 0; ni < 4; ++ni)
#pragma unroll
          for (int r = 0; r < 4; ++r) ss[r] += acc[mi][ni][r] * acc[mi][ni][r];
#pragma unroll
      for (int off = 1; off < 16; off <<= 1)
#pragma unroll
          for (int r = 0; r < 4; ++r) ss[r] += __shfl_xor(ss[r], off, 64);
#pragma unroll
        for (int r = 0; r < 4; ++r) sc[r] = 1.f / fmaxf(sqrtf(ss[r]), 1e-12f);
      } else {
#pragma unroll
        for (int r = 0; r < 4; ++r) sc[r] = vs;
      }
      const int g = mi * 2 + (quad >> 1);   // n-group (n_local = mi*16+quad*4+r)
      const int sub = (quad & 1) * 4;
#pragma unroll
      for (int ni = 0; ni < 4; ++ni) {
        const int d = ni * 16 + lr;
        uint2 o;
        o.x = (u32)f2bf(acc[mi][ni][0] * sc[0]) | ((u32)f2bf(acc[mi][ni][1] * sc[1]) << 16);
        o.y = (u32)f2bf(acc[mi][ni][2] * sc[2]) | ((u32)f2bf(acc[mi][ni][3] * sc[3]) << 16);
        *(uint2*)&LT[d * 128 + ((g ^ (d & 15)) << 3) + sub] = o;
      }
    }
    __syncthreads();  // uniform (sel uniform per block); orders LDS writes
    const int d = lane;
    u16* drow = Tw + (size_t)d * 4352 + nglob0;
#pragma unroll
    for (int j = 0; j < 16; ++j) {
      const uint4 qv = *(const uint4*)&LT[d * 128 + ((j ^ (d & 15)) << 3)];
      *(uint4*)&drow[j * 8] = qv;
    }
  }
}

// ---------- kv via MFMA, split-K partials (NO atomics) ----------
// grid (64, 17): block (bh, y) covers K-steps 4y..4y+3 (one 64-step per wave;
// 17*4 = 68 = 4352/64 exactly). Per-block 4-way LDS reduce, then plain coalesced
// stores of the 16KB partial to kvp[y][bh]. kv_reduce sums the 17 partials.
__global__ __launch_bounds__(256) void kv_mfma(
    const u16* __restrict__ Kt, const u16* __restrict__ Vt, float* __restrict__ kvp) {
  __shared__ __align__(16) u16 TT[4][2][4096];  // per wave: K tile, V tile (64x64 u16)
  const int bh = blockIdx.x;
  const int t = threadIdx.x;
  const int w = t >> 6;
  const int lane = t & 63;
  const int lr = lane & 15;
  const int quad = lane >> 4;
  const u16* Ksrc = Kt + (size_t)bh * 64 * 4352;
  const u16* Vsrc = Vt + (size_t)bh * 64 * 4352;
  const int row8 = lane >> 3;
  const int gst = lane & 7;
  fx4 acc[4][4] = {};

  const int kbase = (blockIdx.y * 4 + w) * 64;  // this wave's K-step
#pragma unroll
  for (int i = 0; i < 8; ++i) {
    const int row = i * 8 + row8;
    const int col = ((gst ^ (row & 7)) << 3);
    const size_t go = (size_t)row * 4352 + kbase + col;
    async_copy16(Ksrc + go, &TT[w][0][i * 512 + lane * 8]);
    async_copy16(Vsrc + go, &TT[w][1][i * 512 + lane * 8]);
  }
  __syncthreads();
#pragma unroll
  for (int ks = 0; ks < 2; ++ks) {
    bfx8 af[4], bfr[4];
    const int g = ((ks * 4 + quad) ^ (lr & 7)) << 3;
#pragma unroll
    for (int i = 0; i < 4; ++i) af[i] = *(const bfx8*)&TT[w][0][(i * 16 + lr) * 64 + g];
#pragma unroll
    for (int i = 0; i < 4; ++i) bfr[i] = *(const bfx8*)&TT[w][1][(i * 16 + lr) * 64 + g];
#pragma unroll
    for (int mi = 0; mi < 4; ++mi)
#pragma unroll
      for (int ni = 0; ni < 4; ++ni)
        acc[mi][ni] =
            __builtin_amdgcn_mfma_f32_16x16x32_bf16(af[mi], bfr[ni], acc[mi][ni], 0, 0, 0);
  }
  __syncthreads();
  // per-wave partial C^T [e][d] f32, d-group swizzled; then 4-way reduce
  float* red = (float*)&TT[0][0][0];  // 16384 f32
  float* my = red + w * 4096;
#pragma unroll
  for (int mi = 0; mi < 4; ++mi)
#pragma unroll
    for (int ni = 0; ni < 4; ++ni) {
      const int e = ni * 16 + lr;
      const int dg = mi * 4 + quad;      // d = dg*4 + r, r consecutive in acc
      *(fx4*)&my[e * 64 + ((dg ^ (e & 15)) << 2)] = acc[mi][ni];
    }
  __syncthreads();
  float* outp = kvp + ((size_t)blockIdx.y * 64 + bh) * 4096;
#pragma unroll
  for (int j = 0; j < 4; ++j) {
    const int L = t * 16 + j * 4;        // flat [e][d] index
    const int e = L >> 6;
    const int dg = (L >> 2) & 15;
    const int addr = e * 64 + ((dg ^ (e & 15)) << 2);
    fx4 sv = *(const fx4*)&red[addr];
    sv += *(const fx4*)&red[4096 + addr];
    sv += *(const fx4*)&red[8192 + addr];
    sv += *(const fx4*)&red[12288 + addr];
    *(fx4*)&outp[L] = sv;
  }
}

// ---------- sum the 17 split-K partials: kvb[bh] = sum_y kvp[y][bh] ----------
__global__ __launch_bounds__(256) void kv_reduce(
    const float* __restrict__ kvp, float* __restrict__ kvb) {
  const int o = blockIdx.x * 256 + threadIdx.x;  // fx4 index, 65536 total
  const int bh = o >> 10;
  const int idx = (o & 1023) * 4;
  fx4 s = {0.f, 0.f, 0.f, 0.f};
#pragma unroll
  for (int y = 0; y < 17; ++y)
    s += *(const fx4*)&kvp[((size_t)y * 64 + bh) * 4096 + idx];
  *(fx4*)&kvb[(size_t)bh * 4096 + idx] = s;
}

// ---------- Weff[b][o, h*64+d] = sum_e Wo[o, h*64+e] * kv[b,h][d,e]  (bf16 out) ----------
// kvb holds kv transposed: kvb[bh][e*64+d].
__global__ __launch_bounds__(256) void weff_build(
    const u16* __restrict__ WoX, const u16* __restrict__ WoC,
    const float* __restrict__ kvb, u16* __restrict__ WeffX, u16* __restrict__ WeffC) {
  const int ot = blockIdx.x;
  const int bh = blockIdx.y;
  const int b = bh >> 4, h = bh & 15;
  const u16* Wo = blockIdx.z ? WoC : WoX;
  u16* outp = (blockIdx.z ? WeffC : WeffX) + (size_t)b * 1048576;

  __shared__ __align__(16) float kvT[64 * 64];  // [e][d] = kvb layout, direct copy
  __shared__ __align__(16) float WoT[64 * 64];  // [e][o_local]
  const int t = threadIdx.x;
#pragma unroll
  for (int j = 0; j < 4; ++j) {
    const int idx = (t + 256 * j) * 4;
    *(fx4*)&kvT[idx] = *(const fx4*)&kvb[(size_t)bh * 4096 + idx];
  }
#pragma unroll
  for (int j = 0; j < 2; ++j) {
    const int u = t + 256 * j;  // 512 groups of 8 bf16
    const int row = u >> 3;     // o_local
    const int e0 = (u & 7) * 8;
    const uint4 q = *(const uint4*)&Wo[(size_t)(ot * 64 + row) * 1024 + h * 64 + e0];
    WoT[(e0 + 0) * 64 + row] = bf2f((u16)(q.x & 0xffff));
    WoT[(e0 + 1) * 64 + row] = bf2f((u16)(q.x >> 16));
    WoT[(e0 + 2) * 64 + row] = bf2f((u16)(q.y & 0xffff));
    WoT[(e0 + 3) * 64 + row] = bf2f((u16)(q.y >> 16));
    WoT[(e0 + 4) * 64 + row] = bf2f((u16)(q.z & 0xffff));
    WoT[(e0 + 5) * 64 + row] = bf2f((u16)(q.z >> 16));
    WoT[(e0 + 6) * 64 + row] = bf2f((u16)(q.w & 0xffff));
    WoT[(e0 + 7) * 64 + row] = bf2f((u16)(q.w >> 16));
  }
  __syncthreads();
  const int ob = (t >> 4) * 4;  // o_local base
  const int db = (t & 15) * 4;  // d base
  float acc[4][4] = {};
#pragma unroll 4
  for (int e = 0; e < 64; ++e) {
    const fx4 wv = *(const fx4*)&WoT[e * 64 + ob];
    const fx4 kvv = *(const fx4*)&kvT[e * 64 + db];
#pragma unroll
    for (int i = 0; i < 4; ++i)
#pragma unroll
      for (int j = 0; j < 4; ++j)
        acc[i][j] += wv[i] * kvv[j];
  }
#pragma unroll
  for (int i = 0; i < 4; ++i)
#pragma unroll
    for (int j = 0; j < 4; ++j)
      outp[(size_t)(ot * 64 + ob + i) * 1024 + h * 64 + db + j] = f2bf(acc[i][j]);
}

// ---------- fused output GEMMs: out = q @ Weff[b]^T for x and c streams ----------
// XCD chunked swizzle: u = yt*4 + xx; u = (bid%8)*34 + bid/8 (272 % 8 == 0).
__global__ __launch_bounds__(512, 2) void out_fused(
    const u16* __restrict__ Qx, const u16* __restrict__ Qc,
    const u16* __restrict__ Wex, const u16* __restrict__ Wec,
    float* __restrict__ out) {
  extern __shared__ __align__(16) u16 lds[];
  const int bid = (int)(blockIdx.y * 4 + blockIdx.x);
  const int u = (bid & 7) * 34 + (bid >> 3);
  const int yt = u >> 2;
  const int xx = u & 3;
  const int b = yt / 17;
  const int l = yt - b * 17;
  const bool isC = (l == 16);
  const u16* A;
  const u16* Bw;
  float* C;
  long rowBase;
  if (!isC) {
    A = Qx + (size_t)b * 4194304;
    Bw = Wex + (size_t)b * 1048576;
    C = out + (size_t)b * 4194304;
    rowBase = (long)l * 256;
  } else {
    A = Qc + (size_t)b * 262144;
    Bw = Wec + (size_t)b * 1048576;
    C = out + 16777216 + (size_t)b * 262144;
    rowBase = 0;
  }
  const long colBase = (long)xx * 256;

  fx4 acc[8][4] = {};
  gemm256_core(A, Bw, rowBase, colBase, lds, acc);

  const int t = threadIdx.x;
  const int lane = t & 63;
  const int lr = lane & 15;
  const int quad = lane >> 4;
  const int w = t >> 6;
  const int wr = w >> 2;
  const int wc = w & 3;
#pragma unroll
  for (int mi = 0; mi < 8; ++mi)
#pragma unroll
    for (int ni = 0; ni < 4; ++ni) {
      const long col = colBase + wc * 64 + ni * 16 + lr;
#pragma unroll
      for (int r = 0; r < 4; ++r) {
        const long row = rowBase + wr * 128 + mi * 16 + quad * 4 + r;
        C[row * 1024 + col] = acc[mi][ni][r];
      }
    }
}

// ---------- launch ----------
extern "C" void kernel_launch(void* const* d_in, const int* in_sizes, int n_in,
                              void* d_out, int out_size, void* d_ws, size_t ws_size,
                              hipStream_t stream) {
  (void)in_sizes; (void)n_in; (void)out_size; (void)ws_size;
  const float* x = (const float*)d_in[0];
  const float* c = (const float*)d_in[1];
  const float* nc = (const float*)d_in[10];
  float* out = (float*)d_out;
  char* ws = (char*)d_ws;

  static bool attr_done = false;
  if (!attr_done) {
    hipFuncSetAttribute((const void*)proj_fused,
                        hipFuncAttributeMaxDynamicSharedMemorySize, 131072);
    hipFuncSetAttribute((const void*)out_fused,
                        hipFuncAttributeMaxDynamicSharedMemorySize, 131072);
    attr_done = true;
  }

  // workspace layout (bytes). total = 177,209,344
  u16* Xb = (u16*)(ws + 0);                 // 33,554,432
  u16* Cb = (u16*)(ws + 33554432);          //  2,097,152
  u16* Wb = (u16*)(ws + 35651584);          // 16,777,216 (8 weights bf16)
  u16* Qx = (u16*)(ws + 52428800);          // 33,554,432
  u16* Qc = (u16*)(ws + 85983232);          //  2,097,152
  u16* Kt = (u16*)(ws + 88080384);          // 35,651,584  [b,h][64 d][4352 n]
  u16* Vt = (u16*)(ws + 123731968);         // 35,651,584
  float* kvb = (float*)(ws + 159383552);    //  1,048,576  kv^T: [bh][e*64+d]
  u16* Weffx = (u16*)(ws + 160432128);      //  8,388,608
  u16* Weffc = (u16*)(ws + 168820736);      //  8,388,608
  // split-K partials (17 x 64 x 4096 f32 = 17.8 MB) alias Xb: proj_fused has
  // fully consumed Xb before kv_mfma runs.
  float* kvp = (float*)(ws + 0);

  cvt_all<<<25600, 256, 0, stream>>>(
      x, c, (const float*)d_in[2], (const float*)d_in[3], (const float*)d_in[4],
      (const float*)d_in[5], (const float*)d_in[6], (const float*)d_in[7],
      (const float*)d_in[8], (const float*)d_in[9], Xb, Cb, Wb);

  // all 6 QKV projections in one dispatch (Q row-major; K,V transposed)
  proj_fused<<<dim3(12, 68), 512, 131072, stream>>>(Xb, Cb, Wb, Qx, Qc, Kt, Vt, nc);
  // kv = K^T V per (b,h): split-K partials (plain stores), then reduce
  kv_mfma<<<dim3(64, 17), 256, 0, stream>>>(Kt, Vt, kvp);
  kv_reduce<<<256, 256, 0, stream>>>(kvp, kvb);
  // fold kv into output projections: Weff[b] = blockdiag(kv) applied to Wo
  weff_build<<<dim3(16, 64, 2), 256, 0, stream>>>(Wb + 6 * 1048576, Wb + 7 * 1048576,
                                                  kvb, Weffx, Weffc);
  // both output GEMMs in one dispatch, straight into d_out (fp32)
  out_fused<<<dim3(4, 68), 512, 131072, stream>>>(Qx, Qc, Weffx, Weffc, out);
}